// Round 10
// baseline (298.714 us; speedup 1.0000x reference)
//
#include <hip/hip_runtime.h>
#include <hip/hip_fp16.h>
#include <math.h>

#define D_ 128
#define K_ 1024
#define N_ 65536
#define DECAY_ 0.99f
#define OMD_ 0.01f
#define EPS_ 1e-5f
#define VQC_ 0.25f
#define SSPLIT 4
#define MARGIN_ 0.1f
#define SSQ_PARTS (K_ * SSPLIT)

typedef __attribute__((ext_vector_type(8))) _Float16 half8;
typedef __attribute__((ext_vector_type(4))) float f32x4;

// ---- workspace offsets (in 4-byte elements) ----
#define WOFF_CODE  0          // int[65536]
#define WOFF_E2    65536      // float[1024]
#define WOFF_CNT   66560      // int[1024]
#define WOFF_SSQ   67584      // float[1]
#define WOFF_RCNT  67585      // int[1]    (CNT..RCNT zeroed by k_prep block 0)
#define WOFF_BASE  67648      // int[1025]
#define WOFF_CURS  68736      // int[1024]
#define WOFF_ORDER 69760      // int[65536]
#define WOFF_ET    136320     // float[131072] (K x D), 16B aligned
#define WOFF_PART  267392     // float[SSPLIT * 131072]
#define WOFF_RLIST 791680     // int[65536]; reused as float ssq_part[SSQ_PARTS] by k_segsum
#define WOFF_EF    857216     // ushort[131072] frag-ordered fp16 of -2E

// ---- output offsets (in floats), reference return order ----
#define OOFF_Q     0          // [16,4096,128]
#define OOFF_DIFF  8388608    // scalar
#define OOFF_CODE  8388609    // [16,4096]
#define OOFF_NEMB  8454145    // [128,1024]
#define OOFF_NCS   8585217    // [1024]
#define OOFF_NMEAN 8586241    // [128,1024]

// -------------------------------------------------------------------
// Fused prep: E [D][K] -> Et [K][D], fp16 frag plane Ef of -2E, e2,
// and cnt/ssq/rcnt zeroing (block 0). Block b handles codes 16b..16b+15.
__launch_bounds__(256)
__global__ void k_prep(const float* __restrict__ E, float* __restrict__ Et,
                       unsigned short* __restrict__ Ef, float* __restrict__ e2,
                       int* __restrict__ cnt) {
    __shared__ float tile[128 * 17];   // tile[d][cc], pad 17 vs 16
    __shared__ float e2s[16];
    int tid = threadIdx.x;
    int b = blockIdx.x;                // 0..63
    int c0 = b * 16;
    if (b == 0) {
        for (int i = tid; i < 1026; i += 256) cnt[i] = 0;   // cnt[1024], ssq, rcnt
    }
    if (tid < 16) e2s[tid] = 0.f;
    // ---- load E columns c0..c0+15 (2048 floats) ----
    #pragma unroll
    for (int i = 0; i < 8; ++i) {
        int idx = i * 256 + tid;       // 0..2047
        int d = idx >> 4, cc = idx & 15;
        tile[d * 17 + cc] = E[d * K_ + c0 + cc];
    }
    __syncthreads();
    // ---- write Et rows (coalesced, conflict-free via pad) ----
    #pragma unroll
    for (int i = 0; i < 8; ++i) {
        int idx = i * 256 + tid;
        int cc = idx >> 7, d = idx & 127;
        Et[(size_t)(c0 + cc) * D_ + d] = tile[d * 17 + cc];
    }
    // ---- Ef frags + e2 ----
    int L = tid & 63, s = tid >> 6;
    int cc = L & 15;
    int d0 = s * 32 + ((L >> 4) << 3);
    unsigned short h[8];
    float sq = 0.f;
    #pragma unroll
    for (int j = 0; j < 8; ++j) {
        float e = tile[(d0 + j) * 17 + cc];
        sq = fmaf(e, e, sq);
        h[j] = __half_as_ushort(__float2half(-2.f * e));
    }
    int T = b * 256 + tid;
    #pragma unroll
    for (int j = 0; j < 8; ++j) Ef[T * 8 + j] = h[j];
    atomicAdd(&e2s[cc], sq);
    __syncthreads();
    if (tid < 16) e2[c0 + tid] = e2s[tid];
}

// -------------------------------------------------------------------
// MFMA argmin with register-prefetched staging: while chunk q computes,
// chunk q+1's 16 KB sits in-flight in 4 float4 regs (cp.async analog).
// Block = 64 tokens, 4 waves; wave (mg,ng): 2 m-tiles x n-half ng.
__launch_bounds__(256, 4)
__global__ void k_argmin_mfma(const float* __restrict__ x, const unsigned short* __restrict__ Ef,
                              const float* __restrict__ e2,
                              int* __restrict__ code_i, float* __restrict__ code_f,
                              int* __restrict__ cnt, int* __restrict__ rcnt,
                              int* __restrict__ rlist) {
    __shared__ unsigned short Bs[8192];   // 16 KB, one 64-code chunk (fp16)
    __shared__ float e2s[K_];
    int tid = threadIdx.x;
    int w = tid >> 6, L = tid & 63, quad = L >> 4, col = L & 15;
    int mg = w >> 1, ng = w & 1;
    int n0 = blockIdx.x * 64;

    for (int i = tid; i < K_; i += 256) e2s[i] = e2[i];

    // ---- A fragments: 32 tokens/wave (2 m-tiles), fp16 in registers ----
    half8 ah[2][4];
    #pragma unroll
    for (int mt = 0; mt < 2; ++mt) {
        int tok = n0 + (2 * mg + mt) * 16 + col;
        #pragma unroll
        for (int s = 0; s < 4; ++s) {
            const float* p = x + (size_t)tok * D_ + s * 32 + quad * 8;
            float4 u0 = *(const float4*)(p);
            float4 u1 = *(const float4*)(p + 4);
            ah[mt][s][0] = (_Float16)u0.x; ah[mt][s][1] = (_Float16)u0.y;
            ah[mt][s][2] = (_Float16)u0.z; ah[mt][s][3] = (_Float16)u0.w;
            ah[mt][s][4] = (_Float16)u1.x; ah[mt][s][5] = (_Float16)u1.y;
            ah[mt][s][6] = (_Float16)u1.z; ah[mt][s][7] = (_Float16)u1.w;
        }
    }

    float b1[2][4], b2[2][4];
    int   bi[2][4];
    #pragma unroll
    for (int mt = 0; mt < 2; ++mt)
        #pragma unroll
        for (int r = 0; r < 4; ++r) { b1[mt][r] = INFINITY; b2[mt][r] = INFINITY; bi[mt][r] = 0; }

    // ---- prefetch chunk 0 ----
    float4 pf[4];
    #pragma unroll
    for (int i = 0; i < 4; ++i) pf[i] = ((const float4*)Ef)[i * 256 + tid];

    for (int q = 0; q < 16; ++q) {
        __syncthreads();                  // readers of chunk q-1 done
        #pragma unroll
        for (int i = 0; i < 4; ++i) ((float4*)Bs)[i * 256 + tid] = pf[i];
        __syncthreads();                  // chunk q visible
        if (q < 15) {
            const float4* nx = (const float4*)(Ef + (q + 1) * 8192);
            #pragma unroll
            for (int i = 0; i < 4; ++i) pf[i] = nx[i * 256 + tid];   // in flight during compute
        }

        // ---- acc init = e2 of this lane's column (this wave's code half) ----
        f32x4 acc[2][2];   // [m-tile][n-sub]
        #pragma unroll
        for (int nn = 0; nn < 2; ++nn) {
            float ev = e2s[q * 64 + (2 * ng + nn) * 16 + col];
            acc[0][nn] = (f32x4){ev, ev, ev, ev};
            acc[1][nn] = (f32x4){ev, ev, ev, ev};
        }

        // ---- 16 MFMA: 4 k-steps x 2 n-subs x 2 m-tiles ----
        #pragma unroll
        for (int s = 0; s < 4; ++s) {
            half8 bh[2];
            #pragma unroll
            for (int nn = 0; nn < 2; ++nn) {
                int off = (((2 * ng + nn) * 4 + s) * 64 + L) * 8;
                bh[nn] = *(const half8*)(Bs + off);
            }
            #pragma unroll
            for (int nn = 0; nn < 2; ++nn) {
                #pragma unroll
                for (int mt = 0; mt < 2; ++mt)
                    acc[mt][nn] = __builtin_amdgcn_mfma_f32_16x16x32_f16(ah[mt][s], bh[nn], acc[mt][nn], 0, 0, 0);
            }
        }

        // ---- fold into running top-2 (ascending code idx => first-min) ----
        #pragma unroll
        for (int nn = 0; nn < 2; ++nn) {
            int ci = q * 64 + (2 * ng + nn) * 16 + col;
            #pragma unroll
            for (int mt = 0; mt < 2; ++mt) {
                #pragma unroll
                for (int r = 0; r < 4; ++r) {
                    float d = acc[mt][nn][r];
                    if (d < b1[mt][r]) {
                        b2[mt][r] = b1[mt][r];
                        b1[mt][r] = d;
                        bi[mt][r] = ci;
                    } else {
                        b2[mt][r] = fminf(b2[mt][r], d);
                    }
                }
            }
        }
    }

    // ---- cross-lane merge over 16 cols, then cross-half merge via LDS ----
    __syncthreads();                        // Bs dead; overlay merge arrays
    float* md1 = (float*)Bs;                // [64 tokens][2 halves]
    float* md2 = md1 + 128;
    int*   mi1 = (int*)(md2 + 128);

    #pragma unroll
    for (int mt = 0; mt < 2; ++mt) {
        #pragma unroll
        for (int r = 0; r < 4; ++r) {
            float bd = b1[mt][r];
            float s2 = b2[mt][r];
            int   ii = bi[mt][r];
            #pragma unroll
            for (int m = 1; m < 16; m <<= 1) {
                float ob  = __shfl_xor(bd, m);
                int   oi  = __shfl_xor(ii, m);
                float os2 = __shfl_xor(s2, m);
                float hi  = fmaxf(bd, ob);
                s2 = fminf(hi, fminf(s2, os2));   // exact combined second-best
                if (ob < bd || (ob == bd && oi < ii)) { bd = ob; ii = oi; }
            }
            if (col == 0) {
                int tl = (2 * mg + mt) * 16 + quad * 4 + r;
                md1[tl * 2 + ng] = bd;
                md2[tl * 2 + ng] = s2;
                mi1[tl * 2 + ng] = ii;
            }
        }
    }
    __syncthreads();
    if (tid < 64) {
        float d1a = md1[tid * 2], d1b = md1[tid * 2 + 1];
        float d2a = md2[tid * 2], d2b = md2[tid * 2 + 1];
        int   ia  = mi1[tid * 2], ib  = mi1[tid * 2 + 1];
        float bd; int ii;
        if (d1b < d1a || (d1b == d1a && ib < ia)) { bd = d1b; ii = ib; }
        else                                      { bd = d1a; ii = ia; }
        float s2 = fminf(fmaxf(d1a, d1b), fminf(d2a, d2b));
        int tok = n0 + tid;
        code_i[tok] = ii;
        code_f[tok] = (float)ii;
        atomicAdd(cnt + ii, 1);
        if (s2 - bd < MARGIN_) {              // true top-2 gap below guard band
            int p = atomicAdd(rcnt, 1);
            rlist[p] = tok;
        }
    }
}

// -------------------------------------------------------------------
// exact fp32 re-argmin for near-tie tokens (coalesced, wave-cooperative)
__launch_bounds__(256)
__global__ void k_fix(const float* __restrict__ x, const float* __restrict__ Et,
                      const float* __restrict__ e2, const int* __restrict__ rcnt,
                      const int* __restrict__ rlist, int* __restrict__ code_i,
                      float* __restrict__ code_f, int* __restrict__ cnt) {
    __shared__ float4 xs[32];
    __shared__ float sd[8];
    __shared__ int   si[8];
    int tid = threadIdx.x;
    int lane = tid & 63, w = tid >> 6;
    int half = lane >> 5;
    int q32  = lane & 31;
    int slot = w * 2 + half;     // 0..7: codes c ≡ slot (mod 8)
    int nr = *rcnt;
    for (int it = blockIdx.x; it < nr; it += gridDim.x) {
        __syncthreads();
        int tok = rlist[it];
        if (tid < 32) xs[tid] = ((const float4*)(x + (size_t)tok * D_))[tid];
        __syncthreads();
        float4 xv = xs[q32];
        float bd = INFINITY; int bb = 0;
        for (int c0 = 0; c0 < K_; c0 += 8) {
            int c = c0 + slot;
            float4 e = ((const float4*)(Et + (size_t)c * D_))[q32];
            float dot = xv.x * e.x + xv.y * e.y + xv.z * e.z + xv.w * e.w;
            dot += __shfl_xor(dot, 1);
            dot += __shfl_xor(dot, 2);
            dot += __shfl_xor(dot, 4);
            dot += __shfl_xor(dot, 8);
            dot += __shfl_xor(dot, 16);
            float dist = e2[c] - 2.f * dot;
            if (dist < bd) { bd = dist; bb = c; }   // c ascending => first-min
        }
        if (q32 == 0) { sd[slot] = bd; si[slot] = bb; }
        __syncthreads();
        if (tid == 0) {
            float fb = sd[0]; int fi = si[0];
            #pragma unroll
            for (int s = 1; s < 8; ++s) {
                if (sd[s] < fb || (sd[s] == fb && si[s] < fi)) { fb = sd[s]; fi = si[s]; }
            }
            int ob = code_i[tok];
            if (fi != ob) {
                code_i[tok] = fi;
                code_f[tok] = (float)fi;
                atomicAdd(cnt + ob, -1);
                atomicAdd(cnt + fi, 1);
            }
        }
    }
}

// -------------------------------------------------------------------
// exclusive scan of code histogram -> base, cursor (256 thr, shfl scan)
__launch_bounds__(256)
__global__ void k_scan(const int* __restrict__ cnt, int* __restrict__ base,
                       int* __restrict__ cursor) {
    int t = threadIdx.x;
    int lane = t & 63, wv = t >> 6;
    int c[4];
    #pragma unroll
    for (int j = 0; j < 4; ++j) c[j] = cnt[4 * t + j];
    int s = c[0] + c[1] + c[2] + c[3];
    int ps = s;
    #pragma unroll
    for (int m = 1; m < 64; m <<= 1) {
        int o = __shfl_up(ps, m);
        if (lane >= m) ps += o;
    }
    __shared__ int wtot[4];
    if (lane == 63) wtot[wv] = ps;
    __syncthreads();
    int woff = 0;
    for (int i = 0; i < 4; ++i) if (i < wv) woff += wtot[i];
    int run = woff + ps - s;
    #pragma unroll
    for (int j = 0; j < 4; ++j) {
        cursor[4 * t + j] = run;
        run += c[j];
        base[4 * t + j + 1] = run;
    }
    if (t == 0) base[0] = 0;
}

// -------------------------------------------------------------------
// token-index scatter into code-sorted order list
__global__ void k_scatter(const int* __restrict__ code_i, int* __restrict__ cursor,
                          int* __restrict__ order) {
    int n = blockIdx.x * 256 + threadIdx.x;
    int c = code_i[n];
    int pos = atomicAdd(cursor + c, 1);
    order[pos] = n;
}

// -------------------------------------------------------------------
// fused segment-sum + dequant/straight-through/ssq: block (c, s) owns
// 1/SSPLIT of code c's token list. Et row c loaded ONCE per block.
__launch_bounds__(128)
__global__ void k_segsum(const float* __restrict__ x, const float* __restrict__ Et,
                         const int* __restrict__ order, const int* __restrict__ base,
                         float* __restrict__ part, float* __restrict__ outq,
                         float* __restrict__ ssq_part) {
    int c = blockIdx.x, s = blockIdx.y, d = threadIdx.x;
    float eq = Et[(size_t)c * D_ + d];        // constant for the whole block
    int b0 = base[c], b1 = base[c + 1];
    int cnt = b1 - b0;
    int i0 = b0 + (cnt * s) / SSPLIT;
    int i1 = b0 + (cnt * (s + 1)) / SSPLIT;
    float a0 = 0.f, a1 = 0.f, a2 = 0.f, a3 = 0.f;
    float ssql = 0.f;
    int i = i0;
    for (; i + 4 <= i1; i += 4) {
        int n0 = order[i], n1 = order[i + 1], n2 = order[i + 2], n3 = order[i + 3];
        float x0 = x[(size_t)n0 * D_ + d];
        float x1 = x[(size_t)n1 * D_ + d];
        float x2 = x[(size_t)n2 * D_ + d];
        float x3 = x[(size_t)n3 * D_ + d];
        float q0 = x0 + (eq - x0);            // reference fp32 rounding
        float q1 = x1 + (eq - x1);
        float q2 = x2 + (eq - x2);
        float q3 = x3 + (eq - x3);
        outq[(size_t)n0 * D_ + d] = q0;
        outq[(size_t)n1 * D_ + d] = q1;
        outq[(size_t)n2 * D_ + d] = q2;
        outq[(size_t)n3 * D_ + d] = q3;
        float t0 = q0 - x0, t1 = q1 - x1, t2 = q2 - x2, t3 = q3 - x3;
        ssql += t0 * t0 + t1 * t1 + t2 * t2 + t3 * t3;
        a0 += x0; a1 += x1; a2 += x2; a3 += x3;
    }
    for (; i < i1; ++i) {
        int n = order[i];
        float xv = x[(size_t)n * D_ + d];
        float qv = xv + (eq - xv);
        outq[(size_t)n * D_ + d] = qv;
        float t = qv - xv;
        ssql += t * t;
        a0 += xv;
    }
    part[((size_t)s * K_ + c) * D_ + d] = (a0 + a1) + (a2 + a3);

    // block-reduce ssql (2 waves of 64)
    #pragma unroll
    for (int off = 32; off > 0; off >>= 1) ssql += __shfl_down(ssql, off);
    __shared__ float wsum[2];
    if ((d & 63) == 0) wsum[d >> 6] = ssql;
    __syncthreads();
    if (d == 0) ssq_part[s * K_ + c] = wsum[0] + wsum[1];
}

// -------------------------------------------------------------------
// fused stats + embed: each block redundantly reduces n; block 0 also
// writes out_ncs + out_diff. Then EMA mean + divide for its 256 elems.
__launch_bounds__(256)
__global__ void k_embed(const float* __restrict__ em, const float* __restrict__ part,
                        const int* __restrict__ cnt, const float* __restrict__ csz,
                        const float* __restrict__ ssq_part, float* __restrict__ out_nmean,
                        float* __restrict__ out_nemb, float* __restrict__ out_ncs,
                        float* __restrict__ out_diff) {
    int tid = threadIdx.x;
    __shared__ float red[256];

    // ---- n = sum_k ncs_k (redundant per block) ----
    float ls = 0.f;
    for (int j = tid; j < K_; j += 256) ls += csz[j] * DECAY_ + OMD_ * (float)cnt[j];
    red[tid] = ls;
    __syncthreads();
    for (int off = 128; off > 0; off >>= 1) {
        if (tid < off) red[tid] += red[tid + off];
        __syncthreads();
    }
    float n = red[0];
    __syncthreads();

    if (blockIdx.x == 0) {
        for (int j = tid; j < K_; j += 256)
            out_ncs[j] = csz[j] * DECAY_ + OMD_ * (float)cnt[j];
        float sp = 0.f;
        for (int j = tid; j < SSQ_PARTS; j += 256) sp += ssq_part[j];
        red[tid] = sp;
        __syncthreads();
        for (int off = 128; off > 0; off >>= 1) {
            if (tid < off) red[tid] += red[tid + off];
            __syncthreads();
        }
        if (tid == 0) *out_diff = VQC_ * red[0] / (float)(N_ * D_);
    }

    int i = blockIdx.x * 256 + tid;           // over D*K, layout [D][K]
    int k = i & (K_ - 1);
    int d = i >> 10;
    float ncs_k = csz[k] * DECAY_ + OMD_ * (float)cnt[k];
    float csk = (ncs_k + EPS_) / (n + (float)K_ * EPS_) * n;
    float es = 0.f;
    #pragma unroll
    for (int s = 0; s < SSPLIT; ++s) es += part[((size_t)s * K_ + k) * D_ + d];
    float nm = em[i] * DECAY_ + OMD_ * es;
    out_nmean[i] = nm;
    out_nemb[i]  = nm / csk;
}

// -------------------------------------------------------------------
extern "C" void kernel_launch(void* const* d_in, const int* in_sizes, int n_in,
                              void* d_out, int out_size, void* d_ws, size_t ws_size,
                              hipStream_t stream) {
    const float* x   = (const float*)d_in[0];   // [16,4096,128]
    const float* E   = (const float*)d_in[1];   // [128,1024]
    const float* csz = (const float*)d_in[2];   // [1024]
    const float* em  = (const float*)d_in[3];   // [128,1024]
    float* out = (float*)d_out;
    float* W   = (float*)d_ws;

    int*   code_i = (int*)(W + WOFF_CODE);
    float* e2     = W + WOFF_E2;
    int*   cnt    = (int*)(W + WOFF_CNT);
    int*   rcnt   = (int*)(W + WOFF_RCNT);
    int*   base   = (int*)(W + WOFF_BASE);
    int*   cursor = (int*)(W + WOFF_CURS);
    int*   order  = (int*)(W + WOFF_ORDER);
    float* Et     = W + WOFF_ET;
    float* part   = W + WOFF_PART;
    int*   rlist  = (int*)(W + WOFF_RLIST);
    float* ssq_part = (float*)(W + WOFF_RLIST);   // reuse: rlist dead after k_fix
    unsigned short* Ef = (unsigned short*)(W + WOFF_EF);

    k_prep<<<64, 256, 0, stream>>>(E, Et, Ef, e2, cnt);
    k_argmin_mfma<<<N_ / 64, 256, 0, stream>>>(x, Ef, e2, code_i,
                                               out + OOFF_CODE, cnt, rcnt, rlist);
    k_fix<<<1024, 256, 0, stream>>>(x, Et, e2, rcnt, rlist, code_i, out + OOFF_CODE, cnt);
    k_scan<<<1, 256, 0, stream>>>(cnt, base, cursor);
    k_scatter<<<N_ / 256, 256, 0, stream>>>(code_i, cursor, order);
    k_segsum<<<dim3(K_, SSPLIT), 128, 0, stream>>>(x, Et, order, base, part,
                                                   out + OOFF_Q, ssq_part);
    k_embed<<<(D_ * K_) / 256, 256, 0, stream>>>(em, part, cnt, csz, ssq_part,
                                                 out + OOFF_NMEAN, out + OOFF_NEMB,
                                                 out + OOFF_NCS, out + OOFF_DIFF);
}

// Round 11
// 258.598 us; speedup vs baseline: 1.1551x; 1.1551x over previous
//
#include <hip/hip_runtime.h>
#include <hip/hip_fp16.h>
#include <math.h>

#define D_ 128
#define K_ 1024
#define N_ 65536
#define DECAY_ 0.99f
#define OMD_ 0.01f
#define EPS_ 1e-5f
#define VQC_ 0.25f
#define SSPLIT 4
#define MARGIN_ 0.1f
#define SSQ_PARTS (K_ * SSPLIT)

typedef __attribute__((ext_vector_type(8))) _Float16 half8;
typedef __attribute__((ext_vector_type(4))) float f32x4;

// ---- workspace offsets (in 4-byte elements) ----
#define WOFF_CODE  0          // int[65536]
#define WOFF_E2    65536      // float[1024]
#define WOFF_CNT   66560      // int[1024]
#define WOFF_SSQ   67584      // float[1]
#define WOFF_RCNT  67585      // int[1]    (CNT..RCNT zeroed by k_prep block 0)
#define WOFF_BASE  67648      // int[1025]
#define WOFF_CURS  68736      // int[1024]
#define WOFF_ORDER 69760      // int[65536]
#define WOFF_ET    136320     // float[131072] (K x D), 16B aligned
#define WOFF_PART  267392     // float[SSPLIT * 131072]
#define WOFF_RLIST 791680     // int[65536]; reused as float ssq_part[SSQ_PARTS] by k_segsum
#define WOFF_EF    857216     // ushort[131072] frag-ordered fp16 of -2E

// ---- output offsets (in floats), reference return order ----
#define OOFF_Q     0          // [16,4096,128]
#define OOFF_DIFF  8388608    // scalar
#define OOFF_CODE  8388609    // [16,4096]
#define OOFF_NEMB  8454145    // [128,1024]
#define OOFF_NCS   8585217    // [1024]
#define OOFF_NMEAN 8586241    // [128,1024]

// async global->LDS 16B per lane (direct DMA, no VGPR round-trip)
__device__ __forceinline__ void gld16(const unsigned short* g, unsigned short* l) {
    __builtin_amdgcn_global_load_lds(
        (const __attribute__((address_space(1))) unsigned int*)g,
        (__attribute__((address_space(3))) unsigned int*)l, 16, 0, 0);
}

// -------------------------------------------------------------------
// Fused prep: E [D][K] -> Et [K][D], fp16 frag plane Ef of -2E, e2,
// and cnt/ssq/rcnt zeroing (block 0). Block b handles codes 16b..16b+15.
__launch_bounds__(256)
__global__ void k_prep(const float* __restrict__ E, float* __restrict__ Et,
                       unsigned short* __restrict__ Ef, float* __restrict__ e2,
                       int* __restrict__ cnt) {
    __shared__ float tile[128 * 17];   // tile[d][cc], pad 17 vs 16
    __shared__ float e2s[16];
    int tid = threadIdx.x;
    int b = blockIdx.x;                // 0..63
    int c0 = b * 16;
    if (b == 0) {
        for (int i = tid; i < 1026; i += 256) cnt[i] = 0;   // cnt[1024], ssq, rcnt
    }
    if (tid < 16) e2s[tid] = 0.f;
    // ---- load E columns c0..c0+15 (2048 floats) ----
    #pragma unroll
    for (int i = 0; i < 8; ++i) {
        int idx = i * 256 + tid;       // 0..2047
        int d = idx >> 4, cc = idx & 15;
        tile[d * 17 + cc] = E[d * K_ + c0 + cc];
    }
    __syncthreads();
    // ---- write Et rows (coalesced, conflict-free via pad) ----
    #pragma unroll
    for (int i = 0; i < 8; ++i) {
        int idx = i * 256 + tid;
        int cc = idx >> 7, d = idx & 127;
        Et[(size_t)(c0 + cc) * D_ + d] = tile[d * 17 + cc];
    }
    // ---- Ef frags + e2 ----
    int L = tid & 63, s = tid >> 6;
    int cc = L & 15;
    int d0 = s * 32 + ((L >> 4) << 3);
    unsigned short h[8];
    float sq = 0.f;
    #pragma unroll
    for (int j = 0; j < 8; ++j) {
        float e = tile[(d0 + j) * 17 + cc];
        sq = fmaf(e, e, sq);
        h[j] = __half_as_ushort(__float2half(-2.f * e));
    }
    int T = b * 256 + tid;
    #pragma unroll
    for (int j = 0; j < 8; ++j) Ef[T * 8 + j] = h[j];
    atomicAdd(&e2s[cc], sq);
    __syncthreads();
    if (tid < 16) e2[c0 + tid] = e2s[tid];
}

// -------------------------------------------------------------------
// MFMA argmin, LDS double-buffered with global_load_lds async staging:
// chunk q+1 streams directly into the other 16 KB buffer while chunk q
// computes; one barrier per chunk drains vmcnt after full compute overlap.
// (R10's register prefetch spilled to scratch: WRITE_SIZE 2.4->47 MB.)
__launch_bounds__(256, 4)
__global__ void k_argmin_mfma(const float* __restrict__ x, const unsigned short* __restrict__ Ef,
                              const float* __restrict__ e2,
                              int* __restrict__ code_i, float* __restrict__ code_f,
                              int* __restrict__ cnt, int* __restrict__ rcnt,
                              int* __restrict__ rlist) {
    __shared__ unsigned short Bs[2][8192];   // 2 x 16 KB chunk buffers
    __shared__ float e2s[K_];
    int tid = threadIdx.x;
    int w = tid >> 6, L = tid & 63, quad = L >> 4, col = L & 15;
    int mg = w >> 1, ng = w & 1;
    int n0 = blockIdx.x * 64;

    for (int i = tid; i < K_; i += 256) e2s[i] = e2[i];

    // ---- A fragments: 32 tokens/wave (2 m-tiles), fp16 in registers ----
    half8 ah[2][4];
    #pragma unroll
    for (int mt = 0; mt < 2; ++mt) {
        int tok = n0 + (2 * mg + mt) * 16 + col;
        #pragma unroll
        for (int s = 0; s < 4; ++s) {
            const float* p = x + (size_t)tok * D_ + s * 32 + quad * 8;
            float4 u0 = *(const float4*)(p);
            float4 u1 = *(const float4*)(p + 4);
            ah[mt][s][0] = (_Float16)u0.x; ah[mt][s][1] = (_Float16)u0.y;
            ah[mt][s][2] = (_Float16)u0.z; ah[mt][s][3] = (_Float16)u0.w;
            ah[mt][s][4] = (_Float16)u1.x; ah[mt][s][5] = (_Float16)u1.y;
            ah[mt][s][6] = (_Float16)u1.z; ah[mt][s][7] = (_Float16)u1.w;
        }
    }

    float b1[2][4], b2[2][4];
    int   bi[2][4];
    #pragma unroll
    for (int mt = 0; mt < 2; ++mt)
        #pragma unroll
        for (int r = 0; r < 4; ++r) { b1[mt][r] = INFINITY; b2[mt][r] = INFINITY; bi[mt][r] = 0; }

    // ---- async stage chunk 0 into buffer 0 (4 x 1KB per wave) ----
    #pragma unroll
    for (int i = 0; i < 4; ++i) {
        int o = (w * 4 + i) * 512;           // ushort offset, wave-uniform
        gld16(Ef + o + L * 8, &Bs[0][o]);
    }
    __syncthreads();                          // vmcnt drained by compiler

    for (int q = 0; q < 16; ++q) {
        int cur = q & 1;
        if (q < 15) {
            const unsigned short* src = Ef + (q + 1) * 8192;
            #pragma unroll
            for (int i = 0; i < 4; ++i) {
                int o = (w * 4 + i) * 512;
                gld16(src + o + L * 8, &Bs[cur ^ 1][o]);   // in flight during compute
            }
        }

        // ---- acc init = e2 of this lane's column (this wave's code half) ----
        f32x4 acc[2][2];   // [m-tile][n-sub]
        #pragma unroll
        for (int nn = 0; nn < 2; ++nn) {
            float ev = e2s[q * 64 + (2 * ng + nn) * 16 + col];
            acc[0][nn] = (f32x4){ev, ev, ev, ev};
            acc[1][nn] = (f32x4){ev, ev, ev, ev};
        }

        // ---- 16 MFMA: 4 k-steps x 2 n-subs x 2 m-tiles ----
        #pragma unroll
        for (int s = 0; s < 4; ++s) {
            half8 bh[2];
            #pragma unroll
            for (int nn = 0; nn < 2; ++nn) {
                int off = (((2 * ng + nn) * 4 + s) * 64 + L) * 8;
                bh[nn] = *(const half8*)(&Bs[cur][off]);
            }
            #pragma unroll
            for (int nn = 0; nn < 2; ++nn) {
                #pragma unroll
                for (int mt = 0; mt < 2; ++mt)
                    acc[mt][nn] = __builtin_amdgcn_mfma_f32_16x16x32_f16(ah[mt][s], bh[nn], acc[mt][nn], 0, 0, 0);
            }
        }

        // ---- fold into running top-2 (ascending code idx => first-min) ----
        #pragma unroll
        for (int nn = 0; nn < 2; ++nn) {
            int ci = q * 64 + (2 * ng + nn) * 16 + col;
            #pragma unroll
            for (int mt = 0; mt < 2; ++mt) {
                #pragma unroll
                for (int r = 0; r < 4; ++r) {
                    float d = acc[mt][nn][r];
                    if (d < b1[mt][r]) {
                        b2[mt][r] = b1[mt][r];
                        b1[mt][r] = d;
                        bi[mt][r] = ci;
                    } else {
                        b2[mt][r] = fminf(b2[mt][r], d);
                    }
                }
            }
        }
        __syncthreads();   // next-chunk DMA complete + cur readers done
    }

    // ---- cross-lane merge over 16 cols, then cross-half merge via LDS ----
    float* md1 = (float*)&Bs[0][0];          // [64 tokens][2 halves]
    float* md2 = md1 + 128;
    int*   mi1 = (int*)(md2 + 128);

    #pragma unroll
    for (int mt = 0; mt < 2; ++mt) {
        #pragma unroll
        for (int r = 0; r < 4; ++r) {
            float bd = b1[mt][r];
            float s2 = b2[mt][r];
            int   ii = bi[mt][r];
            #pragma unroll
            for (int m = 1; m < 16; m <<= 1) {
                float ob  = __shfl_xor(bd, m);
                int   oi  = __shfl_xor(ii, m);
                float os2 = __shfl_xor(s2, m);
                float hi  = fmaxf(bd, ob);
                s2 = fminf(hi, fminf(s2, os2));   // exact combined second-best
                if (ob < bd || (ob == bd && oi < ii)) { bd = ob; ii = oi; }
            }
            if (col == 0) {
                int tl = (2 * mg + mt) * 16 + quad * 4 + r;
                md1[tl * 2 + ng] = bd;
                md2[tl * 2 + ng] = s2;
                mi1[tl * 2 + ng] = ii;
            }
        }
    }
    __syncthreads();
    if (tid < 64) {
        float d1a = md1[tid * 2], d1b = md1[tid * 2 + 1];
        float d2a = md2[tid * 2], d2b = md2[tid * 2 + 1];
        int   ia  = mi1[tid * 2], ib  = mi1[tid * 2 + 1];
        float bd; int ii;
        if (d1b < d1a || (d1b == d1a && ib < ia)) { bd = d1b; ii = ib; }
        else                                      { bd = d1a; ii = ia; }
        float s2 = fminf(fmaxf(d1a, d1b), fminf(d2a, d2b));
        int tok = n0 + tid;
        code_i[tok] = ii;
        code_f[tok] = (float)ii;
        atomicAdd(cnt + ii, 1);
        if (s2 - bd < MARGIN_) {              // true top-2 gap below guard band
            int p = atomicAdd(rcnt, 1);
            rlist[p] = tok;
        }
    }
}

// -------------------------------------------------------------------
// exact fp32 re-argmin for near-tie tokens (coalesced, wave-cooperative)
__launch_bounds__(256)
__global__ void k_fix(const float* __restrict__ x, const float* __restrict__ Et,
                      const float* __restrict__ e2, const int* __restrict__ rcnt,
                      const int* __restrict__ rlist, int* __restrict__ code_i,
                      float* __restrict__ code_f, int* __restrict__ cnt) {
    __shared__ float4 xs[32];
    __shared__ float sd[8];
    __shared__ int   si[8];
    int tid = threadIdx.x;
    int lane = tid & 63, w = tid >> 6;
    int half = lane >> 5;
    int q32  = lane & 31;
    int slot = w * 2 + half;     // 0..7: codes c ≡ slot (mod 8)
    int nr = *rcnt;
    for (int it = blockIdx.x; it < nr; it += gridDim.x) {
        __syncthreads();
        int tok = rlist[it];
        if (tid < 32) xs[tid] = ((const float4*)(x + (size_t)tok * D_))[tid];
        __syncthreads();
        float4 xv = xs[q32];
        float bd = INFINITY; int bb = 0;
        for (int c0 = 0; c0 < K_; c0 += 8) {
            int c = c0 + slot;
            float4 e = ((const float4*)(Et + (size_t)c * D_))[q32];
            float dot = xv.x * e.x + xv.y * e.y + xv.z * e.z + xv.w * e.w;
            dot += __shfl_xor(dot, 1);
            dot += __shfl_xor(dot, 2);
            dot += __shfl_xor(dot, 4);
            dot += __shfl_xor(dot, 8);
            dot += __shfl_xor(dot, 16);
            float dist = e2[c] - 2.f * dot;
            if (dist < bd) { bd = dist; bb = c; }   // c ascending => first-min
        }
        if (q32 == 0) { sd[slot] = bd; si[slot] = bb; }
        __syncthreads();
        if (tid == 0) {
            float fb = sd[0]; int fi = si[0];
            #pragma unroll
            for (int s = 1; s < 8; ++s) {
                if (sd[s] < fb || (sd[s] == fb && si[s] < fi)) { fb = sd[s]; fi = si[s]; }
            }
            int ob = code_i[tok];
            if (fi != ob) {
                code_i[tok] = fi;
                code_f[tok] = (float)fi;
                atomicAdd(cnt + ob, -1);
                atomicAdd(cnt + fi, 1);
            }
        }
    }
}

// -------------------------------------------------------------------
// exclusive scan of code histogram -> base, cursor (256 thr, shfl scan)
__launch_bounds__(256)
__global__ void k_scan(const int* __restrict__ cnt, int* __restrict__ base,
                       int* __restrict__ cursor) {
    int t = threadIdx.x;
    int lane = t & 63, wv = t >> 6;
    int c[4];
    #pragma unroll
    for (int j = 0; j < 4; ++j) c[j] = cnt[4 * t + j];
    int s = c[0] + c[1] + c[2] + c[3];
    int ps = s;
    #pragma unroll
    for (int m = 1; m < 64; m <<= 1) {
        int o = __shfl_up(ps, m);
        if (lane >= m) ps += o;
    }
    __shared__ int wtot[4];
    if (lane == 63) wtot[wv] = ps;
    __syncthreads();
    int woff = 0;
    for (int i = 0; i < 4; ++i) if (i < wv) woff += wtot[i];
    int run = woff + ps - s;
    #pragma unroll
    for (int j = 0; j < 4; ++j) {
        cursor[4 * t + j] = run;
        run += c[j];
        base[4 * t + j + 1] = run;
    }
    if (t == 0) base[0] = 0;
}

// -------------------------------------------------------------------
// token-index scatter into code-sorted order list
__global__ void k_scatter(const int* __restrict__ code_i, int* __restrict__ cursor,
                          int* __restrict__ order) {
    int n = blockIdx.x * 256 + threadIdx.x;
    int c = code_i[n];
    int pos = atomicAdd(cursor + c, 1);
    order[pos] = n;
}

// -------------------------------------------------------------------
// fused segment-sum + dequant/straight-through/ssq: block (c, s) owns
// 1/SSPLIT of code c's token list. Et row c loaded ONCE per block.
__launch_bounds__(128)
__global__ void k_segsum(const float* __restrict__ x, const float* __restrict__ Et,
                         const int* __restrict__ order, const int* __restrict__ base,
                         float* __restrict__ part, float* __restrict__ outq,
                         float* __restrict__ ssq_part) {
    int c = blockIdx.x, s = blockIdx.y, d = threadIdx.x;
    float eq = Et[(size_t)c * D_ + d];        // constant for the whole block
    int b0 = base[c], b1 = base[c + 1];
    int cnt = b1 - b0;
    int i0 = b0 + (cnt * s) / SSPLIT;
    int i1 = b0 + (cnt * (s + 1)) / SSPLIT;
    float a0 = 0.f, a1 = 0.f, a2 = 0.f, a3 = 0.f;
    float ssql = 0.f;
    int i = i0;
    for (; i + 4 <= i1; i += 4) {
        int n0 = order[i], n1 = order[i + 1], n2 = order[i + 2], n3 = order[i + 3];
        float x0 = x[(size_t)n0 * D_ + d];
        float x1 = x[(size_t)n1 * D_ + d];
        float x2 = x[(size_t)n2 * D_ + d];
        float x3 = x[(size_t)n3 * D_ + d];
        float q0 = x0 + (eq - x0);            // reference fp32 rounding
        float q1 = x1 + (eq - x1);
        float q2 = x2 + (eq - x2);
        float q3 = x3 + (eq - x3);
        outq[(size_t)n0 * D_ + d] = q0;
        outq[(size_t)n1 * D_ + d] = q1;
        outq[(size_t)n2 * D_ + d] = q2;
        outq[(size_t)n3 * D_ + d] = q3;
        float t0 = q0 - x0, t1 = q1 - x1, t2 = q2 - x2, t3 = q3 - x3;
        ssql += t0 * t0 + t1 * t1 + t2 * t2 + t3 * t3;
        a0 += x0; a1 += x1; a2 += x2; a3 += x3;
    }
    for (; i < i1; ++i) {
        int n = order[i];
        float xv = x[(size_t)n * D_ + d];
        float qv = xv + (eq - xv);
        outq[(size_t)n * D_ + d] = qv;
        float t = qv - xv;
        ssql += t * t;
        a0 += xv;
    }
    part[((size_t)s * K_ + c) * D_ + d] = (a0 + a1) + (a2 + a3);

    // block-reduce ssql (2 waves of 64)
    #pragma unroll
    for (int off = 32; off > 0; off >>= 1) ssql += __shfl_down(ssql, off);
    __shared__ float wsum[2];
    if ((d & 63) == 0) wsum[d >> 6] = ssql;
    __syncthreads();
    if (d == 0) ssq_part[s * K_ + c] = wsum[0] + wsum[1];
}

// -------------------------------------------------------------------
// fused stats + embed: each block redundantly reduces n; block 0 also
// writes out_ncs + out_diff. Then EMA mean + divide for its 256 elems.
__launch_bounds__(256)
__global__ void k_embed(const float* __restrict__ em, const float* __restrict__ part,
                        const int* __restrict__ cnt, const float* __restrict__ csz,
                        const float* __restrict__ ssq_part, float* __restrict__ out_nmean,
                        float* __restrict__ out_nemb, float* __restrict__ out_ncs,
                        float* __restrict__ out_diff) {
    int tid = threadIdx.x;
    __shared__ float red[256];

    // ---- n = sum_k ncs_k (redundant per block) ----
    float ls = 0.f;
    for (int j = tid; j < K_; j += 256) ls += csz[j] * DECAY_ + OMD_ * (float)cnt[j];
    red[tid] = ls;
    __syncthreads();
    for (int off = 128; off > 0; off >>= 1) {
        if (tid < off) red[tid] += red[tid + off];
        __syncthreads();
    }
    float n = red[0];
    __syncthreads();

    if (blockIdx.x == 0) {
        for (int j = tid; j < K_; j += 256)
            out_ncs[j] = csz[j] * DECAY_ + OMD_ * (float)cnt[j];
        float sp = 0.f;
        for (int j = tid; j < SSQ_PARTS; j += 256) sp += ssq_part[j];
        red[tid] = sp;
        __syncthreads();
        for (int off = 128; off > 0; off >>= 1) {
            if (tid < off) red[tid] += red[tid + off];
            __syncthreads();
        }
        if (tid == 0) *out_diff = VQC_ * red[0] / (float)(N_ * D_);
    }

    int i = blockIdx.x * 256 + tid;           // over D*K, layout [D][K]
    int k = i & (K_ - 1);
    int d = i >> 10;
    float ncs_k = csz[k] * DECAY_ + OMD_ * (float)cnt[k];
    float csk = (ncs_k + EPS_) / (n + (float)K_ * EPS_) * n;
    float es = 0.f;
    #pragma unroll
    for (int s = 0; s < SSPLIT; ++s) es += part[((size_t)s * K_ + k) * D_ + d];
    float nm = em[i] * DECAY_ + OMD_ * es;
    out_nmean[i] = nm;
    out_nemb[i]  = nm / csk;
}

// -------------------------------------------------------------------
extern "C" void kernel_launch(void* const* d_in, const int* in_sizes, int n_in,
                              void* d_out, int out_size, void* d_ws, size_t ws_size,
                              hipStream_t stream) {
    const float* x   = (const float*)d_in[0];   // [16,4096,128]
    const float* E   = (const float*)d_in[1];   // [128,1024]
    const float* csz = (const float*)d_in[2];   // [1024]
    const float* em  = (const float*)d_in[3];   // [128,1024]
    float* out = (float*)d_out;
    float* W   = (float*)d_ws;

    int*   code_i = (int*)(W + WOFF_CODE);
    float* e2     = W + WOFF_E2;
    int*   cnt    = (int*)(W + WOFF_CNT);
    int*   rcnt   = (int*)(W + WOFF_RCNT);
    int*   base   = (int*)(W + WOFF_BASE);
    int*   cursor = (int*)(W + WOFF_CURS);
    int*   order  = (int*)(W + WOFF_ORDER);
    float* Et     = W + WOFF_ET;
    float* part   = W + WOFF_PART;
    int*   rlist  = (int*)(W + WOFF_RLIST);
    float* ssq_part = (float*)(W + WOFF_RLIST);   // reuse: rlist dead after k_fix
    unsigned short* Ef = (unsigned short*)(W + WOFF_EF);

    k_prep<<<64, 256, 0, stream>>>(E, Et, Ef, e2, cnt);
    k_argmin_mfma<<<N_ / 64, 256, 0, stream>>>(x, Ef, e2, code_i,
                                               out + OOFF_CODE, cnt, rcnt, rlist);
    k_fix<<<1024, 256, 0, stream>>>(x, Et, e2, rcnt, rlist, code_i, out + OOFF_CODE, cnt);
    k_scan<<<1, 256, 0, stream>>>(cnt, base, cursor);
    k_scatter<<<N_ / 256, 256, 0, stream>>>(code_i, cursor, order);
    k_segsum<<<dim3(K_, SSPLIT), 128, 0, stream>>>(x, Et, order, base, part,
                                                   out + OOFF_Q, ssq_part);
    k_embed<<<(D_ * K_) / 256, 256, 0, stream>>>(em, part, cnt, csz, ssq_part,
                                                 out + OOFF_NMEAN, out + OOFF_NEMB,
                                                 out + OOFF_NCS, out + OOFF_DIFF);
}